// Round 3
// baseline (7557.089 us; speedup 1.0000x reference)
//
#include <hip/hip_runtime.h>
#include <stdint.h>

// ---------------- problem constants ----------------
#define B_   64
#define T_   256
#define E_   300
#define H_   512
#define PAD_ 1
#define BT_  16384            // B_*T_
#define KP   384              // E padded to 3*128 (wave K-split 96 = 3x32)
#define G_   64               // persistent blocks in recurrence
#define BHB  (64 * 512)       // one hx buffer (elements)

typedef __attribute__((ext_vector_type(8))) short short8;
typedef __attribute__((ext_vector_type(4))) float f32x4;
typedef __attribute__((ext_vector_type(4))) unsigned short us4;
typedef __attribute__((ext_vector_type(8))) unsigned short us8;

// ---------------- helpers ----------------
__device__ __forceinline__ uint16_t f2bf(float f) {           // RNE float->bf16
  uint32_t x = __builtin_bit_cast(uint32_t, f);
  x += 0x7fffu + ((x >> 16) & 1u);
  return (uint16_t)(x >> 16);
}
__device__ __forceinline__ float bf2f(uint16_t u) {
  return __builtin_bit_cast(float, (uint32_t)u << 16);
}
__device__ __forceinline__ float fsig(float x)  { return 1.f / (1.f + __expf(-x)); }
__device__ __forceinline__ float ftanh(float x) { return 1.f - 2.f / (__expf(2.f * x) + 1.f); }

// Monotone (never-reset) grid barrier. bar[0]=arrival count, bar[1]=generation.
__device__ __forceinline__ void grid_barrier(unsigned* bar, unsigned nb) {
  __syncthreads();
  if (threadIdx.x == 0) {
    __builtin_amdgcn_fence(__ATOMIC_RELEASE, "agent");
    unsigned arrival = __hip_atomic_fetch_add(&bar[0], 1u, __ATOMIC_RELAXED, __HIP_MEMORY_SCOPE_AGENT);
    unsigned gen = arrival / nb;
    if (arrival - gen * nb == nb - 1u) {
      __hip_atomic_store(&bar[1], gen + 1u, __ATOMIC_RELAXED, __HIP_MEMORY_SCOPE_AGENT);
    } else {
      while (__hip_atomic_load(&bar[1], __ATOMIC_RELAXED, __HIP_MEMORY_SCOPE_AGENT) <= gen) {}
    }
    __builtin_amdgcn_fence(__ATOMIC_ACQUIRE, "agent");
  }
  __syncthreads();
}

__device__ __forceinline__ void split4(f32x4 v, us4& hi, us4& lo) {
  #pragma unroll
  for (int j = 0; j < 4; ++j) {
    uint16_t h = f2bf(v[j]);
    hi[j] = h;
    lo[j] = f2bf(v[j] - bf2f(h));
  }
}

// ---------------- prep: fp32 -> bf16 hi/lo planes, gathers, zero-init ----------------
__global__ void prep_kernel(
    const float* __restrict__ emb, const float* __restrict__ W_ih,
    const float* __restrict__ b_ih, const float* __restrict__ W_hh,
    const float* __restrict__ b_hh, const float* __restrict__ aW1,
    const float* __restrict__ ab1, const int* __restrict__ x,
    uint16_t* ApH, uint16_t* ApL, uint16_t* WihH, uint16_t* WihL,
    uint16_t* WhhH, uint16_t* WhhL, uint16_t* AW1e,
    float* s1bias, float* biasg,
    uint16_t* hx_hi /* hx_lo contiguous after */, float* amask, float* last, unsigned* bar)
{
  int id = blockIdx.x * 256 + threadIdx.x;
  if (id < 1572864) {                       // Ap hi/lo [m=t*64+b][384]
    int m = id / 96, c = id % 96;
    int t = m >> 6, b = m & 63;
    int tok = x[b * T_ + t];
    f32x4 v = (f32x4){0.f, 0.f, 0.f, 0.f};
    if (tok != PAD_ && c < 75) v = *(const f32x4*)(emb + (size_t)tok * 300 + c * 4);
    us4 hi, lo; split4(v, hi, lo);
    *(us4*)(ApH + (size_t)m * KP + c * 4) = hi;
    *(us4*)(ApL + (size_t)m * KP + c * 4) = lo;
    return;
  }
  id -= 1572864;
  if (id < 196608) {                        // Wih hi/lo [2048][384]
    int n = id / 96, c = id % 96;
    f32x4 v = (f32x4){0.f, 0.f, 0.f, 0.f};
    if (c < 75) v = *(const f32x4*)(W_ih + (size_t)n * 300 + c * 4);
    us4 hi, lo; split4(v, hi, lo);
    *(us4*)(WihH + (size_t)n * KP + c * 4) = hi;
    *(us4*)(WihL + (size_t)n * KP + c * 4) = lo;
    return;
  }
  id -= 196608;
  if (id < 262144) {                        // Whh hi/lo [2048][512]
    int n = id / 128, c = id % 128;
    f32x4 v = *(const f32x4*)(W_hh + (size_t)n * 512 + c * 4);
    us4 hi, lo; split4(v, hi, lo);
    *(us4*)(WhhH + (size_t)n * 512 + c * 4) = hi;
    *(us4*)(WhhL + (size_t)n * 512 + c * 4) = lo;
    return;
  }
  id -= 262144;
  if (id < 36864) {                         // AW1e[384][384] (hi only): aW1[:,:300] padded
    int e = id / 96, c = id % 96;
    f32x4 v = (f32x4){0.f, 0.f, 0.f, 0.f};
    if (e < 300 && c < 75) v = *(const f32x4*)(aW1 + (size_t)e * 812 + c * 4);
    us4 hi;
    #pragma unroll
    for (int j = 0; j < 4; ++j) hi[j] = f2bf(v[j]);
    *(us4*)(AW1e + (size_t)e * KP + c * 4) = hi;
    return;
  }
  id -= 36864;
  if (id < 384) { s1bias[id] = (id < 300) ? ab1[id] : 0.f; return; }
  id -= 384;
  if (id < 2048) { biasg[id] = b_ih[id] + b_hh[id]; return; }
  id -= 2048;
  if (id < 32768) {                         // zero hx_hi + hx_lo (contiguous 256 KiB)
    ((us4*)hx_hi)[id] = (us4){0, 0, 0, 0};
    return;
  }
  id -= 32768;
  if (id < 16384) {                         // amask[t*64+b]
    int t = id >> 6, b = id & 63;
    amask[id] = (x[b * T_ + t] == PAD_) ? 0.f : 1.f;
    return;
  }
  id -= 16384;
  if (id < 8192) { ((f32x4*)last)[id] = (f32x4){0.f, 0.f, 0.f, 0.f}; return; }
  id -= 8192;
  if (id < 64) bar[id] = 0u;                // both barrier sets
}

// ---------------- attention s1 GEMM: S1(bf16) = Ap_hi @ AW1e^T + ab1 ----------------
// M=16384, N=384, K=384; 128x128 tiles, BK=64
__global__ __launch_bounds__(256) void gemm_s1(
    const uint16_t* __restrict__ Ap, const uint16_t* __restrict__ Bw,
    const float* __restrict__ bias, uint16_t* __restrict__ C)
{
  const int nt = blockIdx.x;                // 0..2
  const int mt = blockIdx.y;                // 0..127
  const int tid = threadIdx.x;
  const int lane = tid & 63, w = tid >> 6;
  const int wm = w >> 1, wn = w & 1;
  const int l15 = lane & 15, lq = lane >> 4;
  __shared__ uint16_t As[128 * 64];
  __shared__ uint16_t Bs[128 * 64];
  f32x4 acc[4][4];
  #pragma unroll
  for (int i = 0; i < 4; ++i)
    #pragma unroll
    for (int j = 0; j < 4; ++j) acc[i][j] = (f32x4){0.f, 0.f, 0.f, 0.f};

  for (int kb = 0; kb < KP; kb += 64) {
    __syncthreads();
    #pragma unroll
    for (int c = 0; c < 4; ++c) {
      int lin = c * 256 + tid;
      int row = lin >> 3, col = (lin & 7) * 8;
      *(us8*)(As + row * 64 + col) = *(const us8*)(Ap + (size_t)(mt * 128 + row) * KP + kb + col);
      *(us8*)(Bs + row * 64 + col) = *(const us8*)(Bw + (size_t)(nt * 128 + row) * KP + kb + col);
    }
    __syncthreads();
    #pragma unroll
    for (int ks = 0; ks < 2; ++ks) {
      const int kk = ks * 32 + lq * 8;
      short8 af[4], bf[4];
      #pragma unroll
      for (int i = 0; i < 4; ++i) af[i] = *(const short8*)(As + (wm * 64 + i * 16 + l15) * 64 + kk);
      #pragma unroll
      for (int i = 0; i < 4; ++i) bf[i] = *(const short8*)(Bs + (wn * 64 + i * 16 + l15) * 64 + kk);
      #pragma unroll
      for (int i = 0; i < 4; ++i)
        #pragma unroll
        for (int j = 0; j < 4; ++j)
          acc[i][j] = __builtin_amdgcn_mfma_f32_16x16x32_bf16(af[i], bf[j], acc[i][j], 0, 0, 0);
    }
  }
  #pragma unroll
  for (int j = 0; j < 4; ++j) {
    const int n = nt * 128 + wn * 64 + j * 16 + l15;
    const float bv = bias[n];
    #pragma unroll
    for (int i = 0; i < 4; ++i) {
      const int mrow = mt * 128 + wm * 64 + i * 16 + lq * 4;
      uint16_t* cp = C + (size_t)mrow * KP + n;
      #pragma unroll
      for (int r = 0; r < 4; ++r) cp[(size_t)r * KP] = f2bf(acc[i][j][r] + bv);
    }
  }
}

// ---------------- persistent LSTM recurrence (input GEMM fused in) ----------------
// 64 blocks x 256 thr (4 waves). Block bk owns hidden units [bk*8, bk*8+8) ->
// gate cols {g*512 + bk*8 + u}. Wave w covers K_hh [w*128,+128), K_ih [w*96,+96).
// All weights as bf16 hi+lo VGPR fragments; hx in global as bf16 hi+lo.
// 3-product split (hi*hi + hi*lo + lo*hi) keeps arithmetic ~fp32-accurate.
__global__ __launch_bounds__(256, 1) void rec_kernel(
    const uint16_t* __restrict__ WhhH, const uint16_t* __restrict__ WhhL,
    const uint16_t* __restrict__ WihH, const uint16_t* __restrict__ WihL,
    const uint16_t* __restrict__ ApH, const uint16_t* __restrict__ ApL,
    const float* __restrict__ biasg,     // [2048] b_ih+b_hh
    const float* __restrict__ aarr,      // [T_*64] gate a (mask or att*mask)
    uint16_t* hx_hi, uint16_t* hx_lo,    // [2][64][512] each
    float* last,                         // [64][512] fp32: init in, final out
    unsigned* bar)
{
  const int tid = threadIdx.x, bk = blockIdx.x;
  const int lane = tid & 63, w = tid >> 6;
  const int l15 = lane & 15, lq = lane >> 4;
  const int gh = l15 >> 3, uu = l15 & 7;

  // weight fragments resident in VGPRs: n-tile n2 cols 0..7 -> gate 2*n2, 8..15 -> 2*n2+1
  short8 bhhH[2][4], bhhL[2][4], bihH[2][3], bihL[2][3];
  #pragma unroll
  for (int n2 = 0; n2 < 2; ++n2) {
    const int n = (n2 * 2 + gh) * 512 + bk * 8 + uu;
    #pragma unroll
    for (int ks = 0; ks < 4; ++ks) {
      const size_t off = (size_t)n * 512 + w * 128 + ks * 32 + lq * 8;
      bhhH[n2][ks] = *(const short8*)(WhhH + off);
      bhhL[n2][ks] = *(const short8*)(WhhL + off);
    }
    #pragma unroll
    for (int kb = 0; kb < 3; ++kb) {
      const size_t off = (size_t)n * KP + w * 96 + kb * 32 + lq * 8;
      bihH[n2][kb] = *(const short8*)(WihH + off);
      bihL[n2][kb] = *(const short8*)(WihL + off);
    }
  }

  // per-thread epilogue ownership: batch eb, units (eu, eu+1)
  const int eb = tid >> 2;
  const int eu = (tid & 3) * 2;
  float2 bg2[4];
  #pragma unroll
  for (int g = 0; g < 4; ++g) bg2[g] = *(const float2*)(biasg + g * 512 + bk * 8 + eu);
  float hprev0 = last[eb * 512 + bk * 8 + eu];
  float hprev1 = last[eb * 512 + bk * 8 + eu + 1];
  float cprev0 = 0.f, cprev1 = 0.f;

  __shared__ float part[4][64][33];      // K-split partials, +1 col pad

  #pragma clang loop unroll(disable)
  for (int t = 0; t < T_; ++t) {
    const size_t ap_base = (size_t)t * 64 * KP;
    const volatile uint16_t* hh = hx_hi + (t & 1) * BHB;
    const volatile uint16_t* hl = hx_lo + (t & 1) * BHB;

    f32x4 acc[4][2];
    #pragma unroll
    for (int mi = 0; mi < 4; ++mi) { acc[mi][0] = (f32x4){0,0,0,0}; acc[mi][1] = (f32x4){0,0,0,0}; }

    // input-side gates: xe @ W_ih^T (recurrence-independent)
    #pragma unroll
    for (int kb = 0; kb < 3; ++kb) {
      const int k = w * 96 + kb * 32 + lq * 8;
      #pragma unroll
      for (int mi = 0; mi < 4; ++mi) {
        const size_t aoff = ap_base + (size_t)(mi * 16 + l15) * KP + k;
        short8 aH = *(const short8*)(ApH + aoff);
        short8 aL = *(const short8*)(ApL + aoff);
        #pragma unroll
        for (int n2 = 0; n2 < 2; ++n2) {
          acc[mi][n2] = __builtin_amdgcn_mfma_f32_16x16x32_bf16(aH, bihH[n2][kb], acc[mi][n2], 0, 0, 0);
          acc[mi][n2] = __builtin_amdgcn_mfma_f32_16x16x32_bf16(aH, bihL[n2][kb], acc[mi][n2], 0, 0, 0);
          acc[mi][n2] = __builtin_amdgcn_mfma_f32_16x16x32_bf16(aL, bihH[n2][kb], acc[mi][n2], 0, 0, 0);
        }
      }
    }
    // recurrent gates: hx @ W_hh^T
    #pragma unroll
    for (int ks = 0; ks < 4; ++ks) {
      const int k = w * 128 + ks * 32 + lq * 8;
      #pragma unroll
      for (int mi = 0; mi < 4; ++mi) {
        const int m = mi * 16 + l15;
        short8 hH = *(const volatile short8*)(hh + m * 512 + k);
        short8 hL = *(const volatile short8*)(hl + m * 512 + k);
        #pragma unroll
        for (int n2 = 0; n2 < 2; ++n2) {
          acc[mi][n2] = __builtin_amdgcn_mfma_f32_16x16x32_bf16(hH, bhhH[n2][ks], acc[mi][n2], 0, 0, 0);
          acc[mi][n2] = __builtin_amdgcn_mfma_f32_16x16x32_bf16(hH, bhhL[n2][ks], acc[mi][n2], 0, 0, 0);
          acc[mi][n2] = __builtin_amdgcn_mfma_f32_16x16x32_bf16(hL, bhhH[n2][ks], acc[mi][n2], 0, 0, 0);
        }
      }
    }

    // K-partials to LDS: D row=(lq*4+r)=batch, col=l15 within n-tile
    #pragma unroll
    for (int mi = 0; mi < 4; ++mi)
      #pragma unroll
      for (int n2 = 0; n2 < 2; ++n2)
        #pragma unroll
        for (int r = 0; r < 4; ++r)
          part[w][mi * 16 + lq * 4 + r][n2 * 16 + l15] = acc[mi][n2][r];

    const float a = aarr[t * 64 + eb];
    __syncthreads();

    // epilogue: gates -> gated (c,h) update for (eb, eu/eu+1)
    float gv0[4], gv1[4];
    #pragma unroll
    for (int g = 0; g < 4; ++g) {
      float s0 = bg2[g].x, s1 = bg2[g].y;
      #pragma unroll
      for (int ww = 0; ww < 4; ++ww) {
        s0 += part[ww][eb][g * 8 + eu];
        s1 += part[ww][eb][g * 8 + eu + 1];
      }
      gv0[g] = s0; gv1[g] = s1;
    }
    float i0 = fsig(gv0[0]), f0 = fsig(gv0[1]), g0 = ftanh(gv0[2]), o0 = fsig(gv0[3]);
    float i1 = fsig(gv1[0]), f1 = fsig(gv1[1]), g1 = ftanh(gv1[2]), o1 = fsig(gv1[3]);
    float cn0 = f0 * cprev0 + i0 * g0;
    float cn1 = f1 * cprev1 + i1 * g1;
    float hn0 = o0 * ftanh(cn0);
    float hn1 = o1 * ftanh(cn1);
    float h0 = a * hn0 + (1.f - a) * hprev0;
    float h1 = a * hn1 + (1.f - a) * hprev1;
    float c0 = a * cn0 + (1.f - a) * cprev0;
    float c1 = a * cn1 + (1.f - a) * cprev1;
    hprev0 = h0; cprev0 = c0; hprev1 = h1; cprev1 = c1;

    {  // publish h as bf16 hi+lo via agent-scope stores
      const int nbuf = (t + 1) & 1;
      uint16_t b0 = f2bf(h0), b1 = f2bf(h1);
      uint16_t l0 = f2bf(h0 - bf2f(b0)), l1 = f2bf(h1 - bf2f(b1));
      uint32_t* ph = (uint32_t*)(hx_hi + nbuf * BHB + eb * 512 + bk * 8 + eu);
      uint32_t* pl = (uint32_t*)(hx_lo + nbuf * BHB + eb * 512 + bk * 8 + eu);
      __hip_atomic_store(ph, (uint32_t)b0 | ((uint32_t)b1 << 16), __ATOMIC_RELAXED, __HIP_MEMORY_SCOPE_AGENT);
      __hip_atomic_store(pl, (uint32_t)l0 | ((uint32_t)l1 << 16), __ATOMIC_RELAXED, __HIP_MEMORY_SCOPE_AGENT);
    }
    if (t == T_ - 1) {
      float2 lv; lv.x = h0; lv.y = h1;
      *(float2*)(last + eb * 512 + bk * 8 + eu) = lv;
    }

    if (t < T_ - 1) grid_barrier(bar, G_);
  }
}

// ---------------- attention between iterations (all fp32) ----------------
__global__ void att1_kernel(const float* __restrict__ last, const float* __restrict__ aW1,
                            float* __restrict__ hterm) {
  int id = blockIdx.x * 256 + threadIdx.x;           // 64*300
  if (id >= 64 * 300) return;
  int b = id / 300, e = id % 300;
  const float* lr = last + b * 512;
  const float* wr = aW1 + (size_t)e * 812 + 300;     // aW1[e, E+k]
  float s = 0.f;
  #pragma unroll 8
  for (int k = 0; k < 512; ++k) s += lr[k] * wr[k];
  hterm[b * 300 + e] = s;
}

__global__ void att2_kernel(const uint16_t* __restrict__ S1, const float* __restrict__ hterm,
                            const float* __restrict__ aW2, const float* __restrict__ ab2,
                            const float* __restrict__ amask, float* __restrict__ att) {
  int id = blockIdx.x * 128 + threadIdx.x;           // t*64+b
  if (id >= BT_) return;
  int b = id & 63;
  const uint16_t* s1 = S1 + (size_t)id * KP;         // inp@aW1[:,:E]^T + ab1 (bf16)
  const float* ht = hterm + b * 300;
  float s = ab2[0];
  for (int e = 0; e < 300; ++e) s += ftanh(bf2f(s1[e]) + ht[e]) * aW2[e];
  att[id] = amask[id] * fsig(s);
}

// ---------------- final logits (fp32 in, fp32 out) ----------------
__global__ void logits_kernel(const float* __restrict__ last, const float* __restrict__ Wout,
                              const float* __restrict__ bout, float* __restrict__ out) {
  int tid = threadIdx.x;                             // 320 = 64*5
  if (tid >= 320) return;
  int b = tid / 5, o = tid % 5;
  const float* lr = last + b * 512;
  const float* wr = Wout + o * 512;
  float s = bout[o];
  #pragma unroll 8
  for (int k = 0; k < 512; ++k) s += lr[k] * wr[k];
  out[tid] = s;
}

// ---------------- workspace layout (bytes, 256-aligned) ----------------
#define OFF_APHI  ((size_t)0)            // 16384*384*2 = 12,582,912
#define OFF_APLO  ((size_t)12582912)
#define OFF_WIHHI ((size_t)25165824)     // 2048*384*2 = 1,572,864
#define OFF_WIHLO ((size_t)26738688)
#define OFF_WHHHI ((size_t)28311552)     // 2048*512*2 = 2,097,152
#define OFF_WHHLO ((size_t)30408704)
#define OFF_AW1E  ((size_t)32505856)     // 384*384*2 = 294,912
#define OFF_S1    ((size_t)32800768)     // 16384*384*2 = 12,582,912 (bf16)
#define OFF_S1B   ((size_t)45383680)     // 384*4 -> 1536
#define OFF_BG    ((size_t)45385216)     // 2048*4
#define OFF_HXHI  ((size_t)45393408)     // 2*BHB*2 = 131,072
#define OFF_HXLO  ((size_t)45524480)     // 131,072 (contiguous after HXHI)
#define OFF_AMASK ((size_t)45655552)     // 65,536
#define OFF_ATT   ((size_t)45721088)     // 65,536
#define OFF_HT    ((size_t)45786624)     // 76,800
#define OFF_LAST  ((size_t)45863424)     // 131,072
#define OFF_BAR   ((size_t)45994496)     // 256
#define WS_NEED   ((size_t)45994752)

extern "C" void kernel_launch(void* const* d_in, const int* in_sizes, int n_in,
                              void* d_out, int out_size, void* d_ws, size_t ws_size,
                              hipStream_t stream) {
  const float* emb  = (const float*)d_in[0];
  const float* W_ih = (const float*)d_in[1];
  const float* b_ih = (const float*)d_in[2];
  const float* W_hh = (const float*)d_in[3];
  const float* b_hh = (const float*)d_in[4];
  const float* aW1  = (const float*)d_in[5];
  const float* ab1  = (const float*)d_in[6];
  const float* aW2  = (const float*)d_in[7];
  const float* ab2  = (const float*)d_in[8];
  const float* Wout = (const float*)d_in[9];
  const float* bout = (const float*)d_in[10];
  const int*   x    = (const int*)d_in[11];

  if (ws_size < WS_NEED) return;  // leaves d_out zeroed -> finite diagnostic absmax

  char* ws = (char*)d_ws;
  uint16_t* ApH    = (uint16_t*)(ws + OFF_APHI);
  uint16_t* ApL    = (uint16_t*)(ws + OFF_APLO);
  uint16_t* WihH   = (uint16_t*)(ws + OFF_WIHHI);
  uint16_t* WihL   = (uint16_t*)(ws + OFF_WIHLO);
  uint16_t* WhhH   = (uint16_t*)(ws + OFF_WHHHI);
  uint16_t* WhhL   = (uint16_t*)(ws + OFF_WHHLO);
  uint16_t* AW1e   = (uint16_t*)(ws + OFF_AW1E);
  uint16_t* S1     = (uint16_t*)(ws + OFF_S1);
  float*    s1bias = (float*)(ws + OFF_S1B);
  float*    biasg  = (float*)(ws + OFF_BG);
  uint16_t* hx_hi  = (uint16_t*)(ws + OFF_HXHI);
  uint16_t* hx_lo  = (uint16_t*)(ws + OFF_HXLO);
  float*    amask  = (float*)(ws + OFF_AMASK);
  float*    att    = (float*)(ws + OFF_ATT);
  float*    hterm  = (float*)(ws + OFF_HT);
  float*    last   = (float*)(ws + OFF_LAST);
  unsigned* bar0   = (unsigned*)(ws + OFF_BAR);
  unsigned* bar1   = bar0 + 16;

  prep_kernel<<<8314, 256, 0, stream>>>(emb, W_ih, b_ih, W_hh, b_hh, aW1, ab1, x,
                                        ApH, ApL, WihH, WihL, WhhH, WhhL, AW1e,
                                        s1bias, biasg, hx_hi, amask, last, bar0);
  gemm_s1<<<dim3(3, 128), 256, 0, stream>>>(ApH, AW1e, s1bias, S1);
  // iter 0: a = pad mask (freeze-at-pad == reference semantics for everything consumed)
  rec_kernel<<<G_, 256, 0, stream>>>(WhhH, WhhL, WihH, WihL, ApH, ApL,
                                     biasg, amask, hx_hi, hx_lo, last, bar0);
  att1_kernel<<<75, 256, 0, stream>>>(last, aW1, hterm);
  att2_kernel<<<128, 128, 0, stream>>>(S1, hterm, aW2, ab2, amask, att);
  // iter 1: a = attention * mask
  rec_kernel<<<G_, 256, 0, stream>>>(WhhH, WhhL, WihH, WihL, ApH, ApL,
                                     biasg, att, hx_hi, hx_lo, last, bar1);
  logits_kernel<<<1, 320, 0, stream>>>(last, Wout, bout, (float*)d_out);
}

// Round 4
// 5417.006 us; speedup vs baseline: 1.3951x; 1.3951x over previous
//
#include <hip/hip_runtime.h>
#include <stdint.h>

// ---------------- problem constants ----------------
#define B_   64
#define T_   256
#define E_   300
#define H_   512
#define PAD_ 1
#define BT_  16384            // B_*T_
#define KP   384              // E padded to 3*128 (wave K-split 96 = 3x32)
#define G_   64               // persistent blocks in recurrence
#define HXS  32768            // one hx plane buffer: 64*512 elements

typedef __attribute__((ext_vector_type(8))) short short8;
typedef __attribute__((ext_vector_type(4))) float f32x4;
typedef __attribute__((ext_vector_type(4))) unsigned short us4;
typedef __attribute__((ext_vector_type(8))) unsigned short us8;

// ---------------- helpers ----------------
__device__ __forceinline__ uint16_t f2bf(float f) {           // RNE float->bf16
  uint32_t x = __builtin_bit_cast(uint32_t, f);
  x += 0x7fffu + ((x >> 16) & 1u);
  return (uint16_t)(x >> 16);
}
__device__ __forceinline__ float bf2f(uint16_t u) {
  return __builtin_bit_cast(float, (uint32_t)u << 16);
}
__device__ __forceinline__ float fsig(float x)  { return 1.f / (1.f + __expf(-x)); }
__device__ __forceinline__ float ftanh(float x) { return 1.f - 2.f / (__expf(2.f * x) + 1.f); }

// coherence-point (Infinity Cache) accesses: bypass XCD-private L1/L2
__device__ __forceinline__ unsigned ld_cp(const unsigned* p) {
  unsigned v;
  asm volatile("global_load_dword %0, %1, off sc0 sc1\n\ts_waitcnt vmcnt(0)"
               : "=v"(v) : "v"(p) : "memory");
  return v;
}
__device__ __forceinline__ void st_cp(unsigned* p, unsigned v) {
  asm volatile("global_store_dword %0, %1, off sc0 sc1" :: "v"(p), "v"(v) : "memory");
}

// flag address scatter: 8 cache lines x 8 flags (spreads store serialization,
// keeps the 64-lane poll to 8 line fetches)
__device__ __forceinline__ int flag_idx(int bk) { return (bk & 7) * 16 + (bk >> 3); }

__device__ __forceinline__ void split4(f32x4 v, us4& hi, us4& lo) {
  #pragma unroll
  for (int j = 0; j < 4; ++j) {
    uint16_t h = f2bf(v[j]);
    hi[j] = h;
    lo[j] = f2bf(v[j] - bf2f(h));
  }
}

// ---------------- prep: fp32 -> bf16 hi/lo planes, gathers, zero-init ----------------
__global__ void prep_kernel(
    const float* __restrict__ emb, const float* __restrict__ W_ih,
    const float* __restrict__ b_ih, const float* __restrict__ W_hh,
    const float* __restrict__ b_hh, const float* __restrict__ aW1,
    const float* __restrict__ ab1, const int* __restrict__ x,
    uint16_t* ApH, uint16_t* ApL, uint16_t* WihH, uint16_t* WihL,
    uint16_t* WhhH, uint16_t* WhhL, uint16_t* AW1e,
    float* s1bias, float* biasg,
    uint16_t* hxH, uint16_t* hxL, float* amask, float* last, unsigned* flags)
{
  int id = blockIdx.x * 256 + threadIdx.x;
  if (id < 1572864) {                       // Ap hi/lo [m=t*64+b][384]
    int m = id / 96, c = id % 96;
    int t = m >> 6, b = m & 63;
    int tok = x[b * T_ + t];
    f32x4 v = (f32x4){0.f, 0.f, 0.f, 0.f};
    if (tok != PAD_ && c < 75) v = *(const f32x4*)(emb + (size_t)tok * 300 + c * 4);
    us4 hi, lo; split4(v, hi, lo);
    *(us4*)(ApH + (size_t)m * KP + c * 4) = hi;
    *(us4*)(ApL + (size_t)m * KP + c * 4) = lo;
    return;
  }
  id -= 1572864;
  if (id < 196608) {                        // Wih hi/lo [2048][384]
    int n = id / 96, c = id % 96;
    f32x4 v = (f32x4){0.f, 0.f, 0.f, 0.f};
    if (c < 75) v = *(const f32x4*)(W_ih + (size_t)n * 300 + c * 4);
    us4 hi, lo; split4(v, hi, lo);
    *(us4*)(WihH + (size_t)n * KP + c * 4) = hi;
    *(us4*)(WihL + (size_t)n * KP + c * 4) = lo;
    return;
  }
  id -= 196608;
  if (id < 262144) {                        // Whh hi/lo [2048][512]
    int n = id / 128, c = id % 128;
    f32x4 v = *(const f32x4*)(W_hh + (size_t)n * 512 + c * 4);
    us4 hi, lo; split4(v, hi, lo);
    *(us4*)(WhhH + (size_t)n * 512 + c * 4) = hi;
    *(us4*)(WhhL + (size_t)n * 512 + c * 4) = lo;
    return;
  }
  id -= 262144;
  if (id < 36864) {                         // AW1e[384][384] (hi only): aW1[:,:300] padded
    int e = id / 96, c = id % 96;
    f32x4 v = (f32x4){0.f, 0.f, 0.f, 0.f};
    if (e < 300 && c < 75) v = *(const f32x4*)(aW1 + (size_t)e * 812 + c * 4);
    us4 hi;
    #pragma unroll
    for (int j = 0; j < 4; ++j) hi[j] = f2bf(v[j]);
    *(us4*)(AW1e + (size_t)e * KP + c * 4) = hi;
    return;
  }
  id -= 36864;
  if (id < 384) { s1bias[id] = (id < 300) ? ab1[id] : 0.f; return; }
  id -= 384;
  if (id < 2048) { biasg[id] = b_ih[id] + b_hh[id]; return; }
  id -= 2048;
  if (id < 8192) {                          // zero HX[0] hi+lo (step-0 state)
    ((us4*)hxH)[id] = (us4){0, 0, 0, 0};
    ((us4*)hxL)[id] = (us4){0, 0, 0, 0};
    return;
  }
  id -= 8192;
  if (id < 16384) {                         // amask[t*64+b]
    int t = id >> 6, b = id & 63;
    amask[id] = (x[b * T_ + t] == PAD_) ? 0.f : 1.f;
    return;
  }
  id -= 16384;
  if (id < 8192) { ((f32x4*)last)[id] = (f32x4){0.f, 0.f, 0.f, 0.f}; return; }
  id -= 8192;
  if (id < 2048) flags[id] = 0u;            // both flag sets (2 x 1024 dwords)
}

// ---------------- attention s1 GEMM: S1(bf16) = Ap_hi @ AW1e^T + ab1 ----------------
__global__ __launch_bounds__(256) void gemm_s1(
    const uint16_t* __restrict__ Ap, const uint16_t* __restrict__ Bw,
    const float* __restrict__ bias, uint16_t* __restrict__ C)
{
  const int nt = blockIdx.x;                // 0..2
  const int mt = blockIdx.y;                // 0..127
  const int tid = threadIdx.x;
  const int lane = tid & 63, w = tid >> 6;
  const int wm = w >> 1, wn = w & 1;
  const int l15 = lane & 15, lq = lane >> 4;
  __shared__ uint16_t As[128 * 64];
  __shared__ uint16_t Bs[128 * 64];
  f32x4 acc[4][4];
  #pragma unroll
  for (int i = 0; i < 4; ++i)
    #pragma unroll
    for (int j = 0; j < 4; ++j) acc[i][j] = (f32x4){0.f, 0.f, 0.f, 0.f};

  for (int kb = 0; kb < KP; kb += 64) {
    __syncthreads();
    #pragma unroll
    for (int c = 0; c < 4; ++c) {
      int lin = c * 256 + tid;
      int row = lin >> 3, col = (lin & 7) * 8;
      *(us8*)(As + row * 64 + col) = *(const us8*)(Ap + (size_t)(mt * 128 + row) * KP + kb + col);
      *(us8*)(Bs + row * 64 + col) = *(const us8*)(Bw + (size_t)(nt * 128 + row) * KP + kb + col);
    }
    __syncthreads();
    #pragma unroll
    for (int ks = 0; ks < 2; ++ks) {
      const int kk = ks * 32 + lq * 8;
      short8 af[4], bf[4];
      #pragma unroll
      for (int i = 0; i < 4; ++i) af[i] = *(const short8*)(As + (wm * 64 + i * 16 + l15) * 64 + kk);
      #pragma unroll
      for (int i = 0; i < 4; ++i) bf[i] = *(const short8*)(Bs + (wn * 64 + i * 16 + l15) * 64 + kk);
      #pragma unroll
      for (int i = 0; i < 4; ++i)
        #pragma unroll
        for (int j = 0; j < 4; ++j)
          acc[i][j] = __builtin_amdgcn_mfma_f32_16x16x32_bf16(af[i], bf[j], acc[i][j], 0, 0, 0);
    }
  }
  #pragma unroll
  for (int j = 0; j < 4; ++j) {
    const int n = nt * 128 + wn * 64 + j * 16 + l15;
    const float bv = bias[n];
    #pragma unroll
    for (int i = 0; i < 4; ++i) {
      const int mrow = mt * 128 + wm * 64 + i * 16 + lq * 4;
      uint16_t* cp = C + (size_t)mrow * KP + n;
      #pragma unroll
      for (int r = 0; r < 4; ++r) cp[(size_t)r * KP] = f2bf(acc[i][j][r] + bv);
    }
  }
}

// ---------------- persistent LSTM recurrence ----------------
// 64 blocks x 256 thr (4 waves). Block bk owns hidden units [bk*8, bk*8+8).
// hx in per-step buffers HX[t] (never reused within a kernel) -> plain loads are
// coherent by construction; publishes are sc0/sc1 write-through; sync via flags.
__global__ __launch_bounds__(256, 1) void rec_kernel(
    const uint16_t* __restrict__ WhhH, const uint16_t* __restrict__ WhhL,
    const uint16_t* __restrict__ WihH, const uint16_t* __restrict__ WihL,
    const uint16_t* __restrict__ ApH, const uint16_t* __restrict__ ApL,
    const float* __restrict__ biasg,     // [2048] b_ih+b_hh
    const float* __restrict__ aarr,      // [T_*64] gate a (mask or att*mask)
    uint16_t* __restrict__ hxH,          // base of this iter's HX hi (t=0 buffer)
    uint16_t* __restrict__ hxL,
    float* __restrict__ last,            // [64][512] fp32: init in, final out
    unsigned* __restrict__ flags)        // this iter's 64 scattered flags
{
  const int tid = threadIdx.x, bk = blockIdx.x;
  const int lane = tid & 63, w = tid >> 6;
  const int l15 = lane & 15, lq = lane >> 4;
  const int gh = l15 >> 3, uu = l15 & 7;

  // weight fragments resident in VGPRs: n-tile n2 cols 0..7 -> gate 2*n2, 8..15 -> 2*n2+1
  short8 bhhH[2][4], bhhL[2][4], bihH[2][3], bihL[2][3];
  #pragma unroll
  for (int n2 = 0; n2 < 2; ++n2) {
    const int n = (n2 * 2 + gh) * 512 + bk * 8 + uu;
    #pragma unroll
    for (int ks = 0; ks < 4; ++ks) {
      const size_t off = (size_t)n * 512 + w * 128 + ks * 32 + lq * 8;
      bhhH[n2][ks] = *(const short8*)(WhhH + off);
      bhhL[n2][ks] = *(const short8*)(WhhL + off);
    }
    #pragma unroll
    for (int kb = 0; kb < 3; ++kb) {
      const size_t off = (size_t)n * KP + w * 96 + kb * 32 + lq * 8;
      bihH[n2][kb] = *(const short8*)(WihH + off);
      bihL[n2][kb] = *(const short8*)(WihL + off);
    }
  }

  // per-thread epilogue ownership: batch eb, units (eu, eu+1)
  const int eb = tid >> 2;
  const int eu = (tid & 3) * 2;
  float2 bg2[4];
  #pragma unroll
  for (int g = 0; g < 4; ++g) bg2[g] = *(const float2*)(biasg + g * 512 + bk * 8 + eu);
  float hprev0 = last[eb * 512 + bk * 8 + eu];
  float hprev1 = last[eb * 512 + bk * 8 + eu + 1];
  float cprev0 = 0.f, cprev1 = 0.f;

  __shared__ float part[4][64][36];      // K-split partials; stride 36 -> 2-way (free)

  unsigned* myflag = flags + flag_idx(bk);
  const unsigned* pollp = flags + flag_idx(lane);

  #pragma clang loop unroll(disable)
  for (int t = 0; t < T_; ++t) {
    const size_t ap_base = (size_t)t * 64 * KP;

    f32x4 acc[4][2];
    #pragma unroll
    for (int mi = 0; mi < 4; ++mi) { acc[mi][0] = (f32x4){0,0,0,0}; acc[mi][1] = (f32x4){0,0,0,0}; }

    // (A) input-side gates: xe @ W_ih^T — no dependence on other blocks
    #pragma unroll
    for (int kb = 0; kb < 3; ++kb) {
      const int k = w * 96 + kb * 32 + lq * 8;
      #pragma unroll
      for (int mi = 0; mi < 4; ++mi) {
        const size_t aoff = ap_base + (size_t)(mi * 16 + l15) * KP + k;
        short8 aH = *(const short8*)(ApH + aoff);
        short8 aL = *(const short8*)(ApL + aoff);
        #pragma unroll
        for (int n2 = 0; n2 < 2; ++n2) {
          acc[mi][n2] = __builtin_amdgcn_mfma_f32_16x16x32_bf16(aH, bihH[n2][kb], acc[mi][n2], 0, 0, 0);
          acc[mi][n2] = __builtin_amdgcn_mfma_f32_16x16x32_bf16(aH, bihL[n2][kb], acc[mi][n2], 0, 0, 0);
          acc[mi][n2] = __builtin_amdgcn_mfma_f32_16x16x32_bf16(aL, bihH[n2][kb], acc[mi][n2], 0, 0, 0);
        }
      }
    }

    // (B) wait until all blocks have published hx[t]
    if (t > 0) {
      __syncthreads();
      if (w == 0) {
        const unsigned tgt = (unsigned)t;
        unsigned v;
        do { v = ld_cp(pollp); } while (__ballot(v < tgt) != 0ull);
      }
      __syncthreads();
    }

    // (C) recurrent gates: hx[t] @ W_hh^T (plain loads; per-step buffer is fresh)
    const uint16_t* hh = hxH + (size_t)t * HXS;
    const uint16_t* hl = hxL + (size_t)t * HXS;
    #pragma unroll
    for (int ks = 0; ks < 4; ++ks) {
      const int k = w * 128 + ks * 32 + lq * 8;
      #pragma unroll
      for (int mi = 0; mi < 4; ++mi) {
        const int m = mi * 16 + l15;
        short8 hH = *(const short8*)(hh + m * 512 + k);
        short8 hL = *(const short8*)(hl + m * 512 + k);
        #pragma unroll
        for (int n2 = 0; n2 < 2; ++n2) {
          acc[mi][n2] = __builtin_amdgcn_mfma_f32_16x16x32_bf16(hH, bhhH[n2][ks], acc[mi][n2], 0, 0, 0);
          acc[mi][n2] = __builtin_amdgcn_mfma_f32_16x16x32_bf16(hH, bhhL[n2][ks], acc[mi][n2], 0, 0, 0);
          acc[mi][n2] = __builtin_amdgcn_mfma_f32_16x16x32_bf16(hL, bhhH[n2][ks], acc[mi][n2], 0, 0, 0);
        }
      }
    }

    // (D) K-partials to LDS: D row=(lq*4+r)=batch, col=l15 within n-tile
    #pragma unroll
    for (int mi = 0; mi < 4; ++mi)
      #pragma unroll
      for (int n2 = 0; n2 < 2; ++n2)
        #pragma unroll
        for (int r = 0; r < 4; ++r)
          part[w][mi * 16 + lq * 4 + r][n2 * 16 + l15] = acc[mi][n2][r];

    const float a = aarr[t * 64 + eb];
    __syncthreads();

    // (E) epilogue: gates -> gated (c,h) update for (eb, eu/eu+1)
    float gv0[4], gv1[4];
    #pragma unroll
    for (int g = 0; g < 4; ++g) {
      float s0 = bg2[g].x, s1 = bg2[g].y;
      #pragma unroll
      for (int ww = 0; ww < 4; ++ww) {
        s0 += part[ww][eb][g * 8 + eu];
        s1 += part[ww][eb][g * 8 + eu + 1];
      }
      gv0[g] = s0; gv1[g] = s1;
    }
    float i0 = fsig(gv0[0]), f0 = fsig(gv0[1]), g0 = ftanh(gv0[2]), o0 = fsig(gv0[3]);
    float i1 = fsig(gv1[0]), f1 = fsig(gv1[1]), g1 = ftanh(gv1[2]), o1 = fsig(gv1[3]);
    float cn0 = f0 * cprev0 + i0 * g0;
    float cn1 = f1 * cprev1 + i1 * g1;
    float hn0 = o0 * ftanh(cn0);
    float hn1 = o1 * ftanh(cn1);
    float h0 = a * hn0 + (1.f - a) * hprev0;
    float h1 = a * hn1 + (1.f - a) * hprev1;
    float c0 = a * cn0 + (1.f - a) * cprev0;
    float c1 = a * cn1 + (1.f - a) * cprev1;
    hprev0 = h0; cprev0 = c0; hprev1 = h1; cprev1 = c1;

    // (F) publish h as bf16 hi+lo to HX[t+1] via coherence-point stores
    {
      uint16_t b0 = f2bf(h0), b1 = f2bf(h1);
      uint16_t l0 = f2bf(h0 - bf2f(b0)), l1 = f2bf(h1 - bf2f(b1));
      const size_t o = (size_t)(t + 1) * HXS + eb * 512 + bk * 8 + eu;
      st_cp((unsigned*)(hxH + o), (uint32_t)b0 | ((uint32_t)b1 << 16));
      st_cp((unsigned*)(hxL + o), (uint32_t)l0 | ((uint32_t)l1 << 16));
    }
    if (t == T_ - 1) {
      float2 lv; lv.x = h0; lv.y = h1;
      *(float2*)(last + eb * 512 + bk * 8 + eu) = lv;
    } else {
      asm volatile("s_waitcnt vmcnt(0)" ::: "memory");   // drain asm stores
      __syncthreads();                                   // all waves drained
      if (tid == 0) st_cp(myflag, (unsigned)(t + 1));
    }
  }
}

// ---------------- attention between iterations (all fp32) ----------------
__global__ void att1_kernel(const float* __restrict__ last, const float* __restrict__ aW1,
                            float* __restrict__ hterm) {
  int id = blockIdx.x * 256 + threadIdx.x;           // 64*300
  if (id >= 64 * 300) return;
  int b = id / 300, e = id % 300;
  const float* lr = last + b * 512;
  const float* wr = aW1 + (size_t)e * 812 + 300;     // aW1[e, E+k]
  float s = 0.f;
  #pragma unroll 8
  for (int k = 0; k < 512; ++k) s += lr[k] * wr[k];
  hterm[b * 300 + e] = s;
}

__global__ void att2_kernel(const uint16_t* __restrict__ S1, const float* __restrict__ hterm,
                            const float* __restrict__ aW2, const float* __restrict__ ab2,
                            const float* __restrict__ amask, float* __restrict__ att) {
  int id = blockIdx.x * 128 + threadIdx.x;           // t*64+b
  if (id >= BT_) return;
  int b = id & 63;
  const uint16_t* s1 = S1 + (size_t)id * KP;         // inp@aW1[:,:E]^T + ab1 (bf16)
  const float* ht = hterm + b * 300;
  float s = ab2[0];
  for (int e = 0; e < 300; ++e) s += ftanh(bf2f(s1[e]) + ht[e]) * aW2[e];
  att[id] = amask[id] * fsig(s);
}

// ---------------- final logits (fp32 in, fp32 out) ----------------
__global__ void logits_kernel(const float* __restrict__ last, const float* __restrict__ Wout,
                              const float* __restrict__ bout, float* __restrict__ out) {
  int tid = threadIdx.x;                             // 320 = 64*5
  if (tid >= 320) return;
  int b = tid / 5, o = tid % 5;
  const float* lr = last + b * 512;
  const float* wr = Wout + o * 512;
  float s = bout[o];
  #pragma unroll 8
  for (int k = 0; k < 512; ++k) s += lr[k] * wr[k];
  out[tid] = s;
}

// ---------------- workspace layout (bytes, 256-aligned) ----------------
#define OFF_APHI  ((size_t)0)            // 16384*384*2 = 12,582,912
#define OFF_APLO  ((size_t)12582912)
#define OFF_WIHHI ((size_t)25165824)     // 2048*384*2 = 1,572,864
#define OFF_WIHLO ((size_t)26738688)
#define OFF_WHHHI ((size_t)28311552)     // 2048*512*2 = 2,097,152
#define OFF_WHHLO ((size_t)30408704)
#define OFF_AW1E  ((size_t)32505856)     // 384*384*2 = 294,912
#define OFF_S1    ((size_t)32800768)     // 16384*384*2 = 12,582,912 (bf16)
#define OFF_S1B   ((size_t)45383680)     // 1536
#define OFF_BG    ((size_t)45385216)     // 8192
#define OFF_HXH   ((size_t)45393408)     // 513*65536 = 33,619,968
#define OFF_HXL   ((size_t)79013376)     // 33,619,968
#define OFF_AMASK ((size_t)112633344)    // 65,536
#define OFF_ATT   ((size_t)112698880)    // 65,536
#define OFF_HT    ((size_t)112764416)    // 76,800
#define OFF_LAST  ((size_t)112841216)    // 131,072
#define OFF_FLG   ((size_t)112972288)    // 8,192 (2 sets x 1024 dwords)
#define WS_NEED   ((size_t)112980480)

extern "C" void kernel_launch(void* const* d_in, const int* in_sizes, int n_in,
                              void* d_out, int out_size, void* d_ws, size_t ws_size,
                              hipStream_t stream) {
  const float* emb  = (const float*)d_in[0];
  const float* W_ih = (const float*)d_in[1];
  const float* b_ih = (const float*)d_in[2];
  const float* W_hh = (const float*)d_in[3];
  const float* b_hh = (const float*)d_in[4];
  const float* aW1  = (const float*)d_in[5];
  const float* ab1  = (const float*)d_in[6];
  const float* aW2  = (const float*)d_in[7];
  const float* ab2  = (const float*)d_in[8];
  const float* Wout = (const float*)d_in[9];
  const float* bout = (const float*)d_in[10];
  const int*   x    = (const int*)d_in[11];

  if (ws_size < WS_NEED) return;  // guarded fail: d_out stays zero (diagnostic)

  char* ws = (char*)d_ws;
  uint16_t* ApH    = (uint16_t*)(ws + OFF_APHI);
  uint16_t* ApL    = (uint16_t*)(ws + OFF_APLO);
  uint16_t* WihH   = (uint16_t*)(ws + OFF_WIHHI);
  uint16_t* WihL   = (uint16_t*)(ws + OFF_WIHLO);
  uint16_t* WhhH   = (uint16_t*)(ws + OFF_WHHHI);
  uint16_t* WhhL   = (uint16_t*)(ws + OFF_WHHLO);
  uint16_t* AW1e   = (uint16_t*)(ws + OFF_AW1E);
  uint16_t* S1     = (uint16_t*)(ws + OFF_S1);
  float*    s1bias = (float*)(ws + OFF_S1B);
  float*    biasg  = (float*)(ws + OFF_BG);
  uint16_t* HXH    = (uint16_t*)(ws + OFF_HXH);
  uint16_t* HXL    = (uint16_t*)(ws + OFF_HXL);
  float*    amask  = (float*)(ws + OFF_AMASK);
  float*    att    = (float*)(ws + OFF_ATT);
  float*    hterm  = (float*)(ws + OFF_HT);
  float*    last   = (float*)(ws + OFF_LAST);
  unsigned* flg0   = (unsigned*)(ws + OFF_FLG);
  unsigned* flg1   = flg0 + 1024;

  prep_kernel<<<8226, 256, 0, stream>>>(emb, W_ih, b_ih, W_hh, b_hh, aW1, ab1, x,
                                        ApH, ApL, WihH, WihL, WhhH, WhhL, AW1e,
                                        s1bias, biasg, HXH, HXL, amask, last, flg0);
  gemm_s1<<<dim3(3, 128), 256, 0, stream>>>(ApH, AW1e, s1bias, S1);
  // iter 0: a = pad mask; uses HX buffers [0..256]
  rec_kernel<<<G_, 256, 0, stream>>>(WhhH, WhhL, WihH, WihL, ApH, ApL,
                                     biasg, amask, HXH, HXL, last, flg0);
  att1_kernel<<<75, 256, 0, stream>>>(last, aW1, hterm);
  att2_kernel<<<128, 128, 0, stream>>>(S1, hterm, aW2, ab2, amask, att);
  // iter 1: a = attention * mask; HX base shifted so its t=0 state = iter0's final
  rec_kernel<<<G_, 256, 0, stream>>>(WhhH, WhhL, WihH, WihL, ApH, ApL,
                                     biasg, att, HXH + (size_t)256 * HXS,
                                     HXL + (size_t)256 * HXS, last, flg1);
  logits_kernel<<<1, 320, 0, stream>>>(last, Wout, bout, (float*)d_out);
}

// Round 5
// 3244.691 us; speedup vs baseline: 2.3291x; 1.6695x over previous
//
#include <hip/hip_runtime.h>
#include <stdint.h>

// ---------------- problem constants ----------------
#define B_   64
#define T_   256
#define E_   300
#define H_   512
#define PAD_ 1
#define BT_  16384            // B_*T_
#define KP   384              // E padded to 3*128 (wave K-split 96 = 3x32)
#define G_   64               // blocks per group in recurrence
#define HXG  16384            // one group hx plane: 32*512 elements
#define HXS  32768            // per-step plane stride (2 groups)

typedef __attribute__((ext_vector_type(8))) short short8;
typedef __attribute__((ext_vector_type(4))) float f32x4;
typedef __attribute__((ext_vector_type(4))) unsigned short us4;
typedef __attribute__((ext_vector_type(8))) unsigned short us8;

// ---------------- helpers ----------------
__device__ __forceinline__ uint16_t f2bf(float f) {           // RNE float->bf16
  uint32_t x = __builtin_bit_cast(uint32_t, f);
  x += 0x7fffu + ((x >> 16) & 1u);
  return (uint16_t)(x >> 16);
}
__device__ __forceinline__ float bf2f(uint16_t u) {
  return __builtin_bit_cast(float, (uint32_t)u << 16);
}
__device__ __forceinline__ float fsig(float x)  { return 1.f / (1.f + __expf(-x)); }
__device__ __forceinline__ float ftanh(float x) { return 1.f - 2.f / (__expf(2.f * x) + 1.f); }

// coherence-point (MALL) accesses: bypass XCD-private L1/L2; self-draining
// (vmcnt(0) inside) so compiler vmcnt bookkeeping stays valid.
__device__ __forceinline__ unsigned ld_cp(const unsigned* p) {
  unsigned v;
  asm volatile("global_load_dword %0, %1, off sc0 sc1\n\ts_waitcnt vmcnt(0)"
               : "=v"(v) : "v"(p) : "memory");
  return v;
}
__device__ __forceinline__ void st_cp(unsigned* p, unsigned v) {
  asm volatile("global_store_dword %0, %1, off sc0 sc1" :: "v"(p), "v"(v) : "memory");
}
// poll monotone counter until >= tgt, with sleep backoff
__device__ __forceinline__ void wait_cnt(const unsigned* p, unsigned tgt) {
  if (ld_cp(p) >= tgt) return;
  do { __builtin_amdgcn_s_sleep(2); } while (ld_cp(p) < tgt);
}

__device__ __forceinline__ void split4(f32x4 v, us4& hi, us4& lo) {
  #pragma unroll
  for (int j = 0; j < 4; ++j) {
    uint16_t h = f2bf(v[j]);
    hi[j] = h;
    lo[j] = f2bf(v[j] - bf2f(h));
  }
}

// ---------------- prep: fp32 -> bf16 hi/lo planes, gathers, zero-init ----------------
__global__ void prep_kernel(
    const float* __restrict__ emb, const float* __restrict__ W_ih,
    const float* __restrict__ b_ih, const float* __restrict__ W_hh,
    const float* __restrict__ b_hh, const float* __restrict__ aW1,
    const float* __restrict__ ab1, const int* __restrict__ x,
    uint16_t* ApH, uint16_t* ApL, uint16_t* WihH, uint16_t* WihL,
    uint16_t* WhhH, uint16_t* WhhL, uint16_t* AW1e,
    float* s1bias, float* biasg,
    uint16_t* hxH, uint16_t* hxL, float* amask, float* last, unsigned* cnts)
{
  int id = blockIdx.x * 256 + threadIdx.x;
  if (id < 1572864) {                       // Ap hi/lo [m=t*64+b][384]
    int m = id / 96, c = id % 96;
    int t = m >> 6, b = m & 63;
    int tok = x[b * T_ + t];
    f32x4 v = (f32x4){0.f, 0.f, 0.f, 0.f};
    if (tok != PAD_ && c < 75) v = *(const f32x4*)(emb + (size_t)tok * 300 + c * 4);
    us4 hi, lo; split4(v, hi, lo);
    *(us4*)(ApH + (size_t)m * KP + c * 4) = hi;
    *(us4*)(ApL + (size_t)m * KP + c * 4) = lo;
    return;
  }
  id -= 1572864;
  if (id < 196608) {                        // Wih hi/lo [2048][384]
    int n = id / 96, c = id % 96;
    f32x4 v = (f32x4){0.f, 0.f, 0.f, 0.f};
    if (c < 75) v = *(const f32x4*)(W_ih + (size_t)n * 300 + c * 4);
    us4 hi, lo; split4(v, hi, lo);
    *(us4*)(WihH + (size_t)n * KP + c * 4) = hi;
    *(us4*)(WihL + (size_t)n * KP + c * 4) = lo;
    return;
  }
  id -= 196608;
  if (id < 262144) {                        // Whh hi/lo [2048][512]
    int n = id / 128, c = id % 128;
    f32x4 v = *(const f32x4*)(W_hh + (size_t)n * 512 + c * 4);
    us4 hi, lo; split4(v, hi, lo);
    *(us4*)(WhhH + (size_t)n * 512 + c * 4) = hi;
    *(us4*)(WhhL + (size_t)n * 512 + c * 4) = lo;
    return;
  }
  id -= 262144;
  if (id < 36864) {                         // AW1e[384][384] (hi only): aW1[:,:300] padded
    int e = id / 96, c = id % 96;
    f32x4 v = (f32x4){0.f, 0.f, 0.f, 0.f};
    if (e < 300 && c < 75) v = *(const f32x4*)(aW1 + (size_t)e * 812 + c * 4);
    us4 hi;
    #pragma unroll
    for (int j = 0; j < 4; ++j) hi[j] = f2bf(v[j]);
    *(us4*)(AW1e + (size_t)e * KP + c * 4) = hi;
    return;
  }
  id -= 36864;
  if (id < 384) { s1bias[id] = (id < 300) ? ab1[id] : 0.f; return; }
  id -= 384;
  if (id < 2048) { biasg[id] = b_ih[id] + b_hh[id]; return; }
  id -= 2048;
  if (id < 8192) {                          // zero HX[0] (both groups) hi+lo
    ((us4*)hxH)[id] = (us4){0, 0, 0, 0};
    ((us4*)hxL)[id] = (us4){0, 0, 0, 0};
    return;
  }
  id -= 8192;
  if (id < 16384) {                         // amask[t*64+b]
    int t = id >> 6, b = id & 63;
    amask[id] = (x[b * T_ + t] == PAD_) ? 0.f : 1.f;
    return;
  }
  id -= 16384;
  if (id < 8192) { ((f32x4*)last)[id] = (f32x4){0.f, 0.f, 0.f, 0.f}; return; }
  id -= 8192;
  if (id < 2048) cnts[id] = 0u;             // all barrier counters
}

// ---------------- attention s1 GEMM: S1(bf16) = Ap_hi @ AW1e^T + ab1 ----------------
__global__ __launch_bounds__(256) void gemm_s1(
    const uint16_t* __restrict__ Ap, const uint16_t* __restrict__ Bw,
    const float* __restrict__ bias, uint16_t* __restrict__ C)
{
  const int nt = blockIdx.x;                // 0..2
  const int mt = blockIdx.y;                // 0..127
  const int tid = threadIdx.x;
  const int lane = tid & 63, w = tid >> 6;
  const int wm = w >> 1, wn = w & 1;
  const int l15 = lane & 15, lq = lane >> 4;
  __shared__ uint16_t As[128 * 64];
  __shared__ uint16_t Bs[128 * 64];
  f32x4 acc[4][4];
  #pragma unroll
  for (int i = 0; i < 4; ++i)
    #pragma unroll
    for (int j = 0; j < 4; ++j) acc[i][j] = (f32x4){0.f, 0.f, 0.f, 0.f};

  for (int kb = 0; kb < KP; kb += 64) {
    __syncthreads();
    #pragma unroll
    for (int c = 0; c < 4; ++c) {
      int lin = c * 256 + tid;
      int row = lin >> 3, col = (lin & 7) * 8;
      *(us8*)(As + row * 64 + col) = *(const us8*)(Ap + (size_t)(mt * 128 + row) * KP + kb + col);
      *(us8*)(Bs + row * 64 + col) = *(const us8*)(Bw + (size_t)(nt * 128 + row) * KP + kb + col);
    }
    __syncthreads();
    #pragma unroll
    for (int ks = 0; ks < 2; ++ks) {
      const int kk = ks * 32 + lq * 8;
      short8 af[4], bf[4];
      #pragma unroll
      for (int i = 0; i < 4; ++i) af[i] = *(const short8*)(As + (wm * 64 + i * 16 + l15) * 64 + kk);
      #pragma unroll
      for (int i = 0; i < 4; ++i) bf[i] = *(const short8*)(Bs + (wn * 64 + i * 16 + l15) * 64 + kk);
      #pragma unroll
      for (int i = 0; i < 4; ++i)
        #pragma unroll
        for (int j = 0; j < 4; ++j)
          acc[i][j] = __builtin_amdgcn_mfma_f32_16x16x32_bf16(af[i], bf[j], acc[i][j], 0, 0, 0);
    }
  }
  #pragma unroll
  for (int j = 0; j < 4; ++j) {
    const int n = nt * 128 + wn * 64 + j * 16 + l15;
    const float bv = bias[n];
    #pragma unroll
    for (int i = 0; i < 4; ++i) {
      const int mrow = mt * 128 + wm * 64 + i * 16 + lq * 4;
      uint16_t* cp = C + (size_t)mrow * KP + n;
      #pragma unroll
      for (int r = 0; r < 4; ++r) cp[(size_t)r * KP] = f2bf(acc[i][j][r] + bv);
    }
  }
}

// ---------------- persistent LSTM recurrence, 2 independent batch groups ----------------
// grid = 128: group g = blockIdx&1 owns samples [g*32, g*32+32); bk = blockIdx>>1 owns
// hidden units [bk*8, bk*8+8). hx in per-step per-group buffers; publishes sc0/sc1
// write-through; sync via monotone arrival counter per group (relaxed atomics, no fences).
__global__ __launch_bounds__(256, 1) void rec_kernel(
    const uint16_t* __restrict__ WhhH, const uint16_t* __restrict__ WhhL,
    const uint16_t* __restrict__ WihH, const uint16_t* __restrict__ WihL,
    const uint16_t* __restrict__ ApH, const uint16_t* __restrict__ ApL,
    const float* __restrict__ biasg,     // [2048] b_ih+b_hh
    const float* __restrict__ aarr,      // [T_*64] gate a (mask or att*mask)
    uint16_t* __restrict__ hxH,          // this iter's HX hi base (t=0 plane)
    uint16_t* __restrict__ hxL,
    float* __restrict__ last,            // [64][512] fp32: init in, final out
    unsigned* __restrict__ cnts)         // this iter's counters (g*64 dword stride)
{
  const int tid = threadIdx.x;
  const int g  = blockIdx.x & 1;
  const int bk = blockIdx.x >> 1;
  const int lane = tid & 63, w = tid >> 6;
  const int l15 = lane & 15, lq = lane >> 4;
  const int gh = l15 >> 3, uu = l15 & 7;

  unsigned* cnt = cnts + g * 64;           // separate cache line per group

  // weight fragments resident in VGPRs: n-tile n2 cols 0..7 -> gate 2*n2, 8..15 -> 2*n2+1
  short8 bhhH[2][4], bhhL[2][4], bihH[2][3], bihL[2][3];
  #pragma unroll
  for (int n2 = 0; n2 < 2; ++n2) {
    const int n = (n2 * 2 + gh) * 512 + bk * 8 + uu;
    #pragma unroll
    for (int ks = 0; ks < 4; ++ks) {
      const size_t off = (size_t)n * 512 + w * 128 + ks * 32 + lq * 8;
      bhhH[n2][ks] = *(const short8*)(WhhH + off);
      bhhL[n2][ks] = *(const short8*)(WhhL + off);
    }
    #pragma unroll
    for (int kb = 0; kb < 3; ++kb) {
      const size_t off = (size_t)n * KP + w * 96 + kb * 32 + lq * 8;
      bihH[n2][kb] = *(const short8*)(WihH + off);
      bihL[n2][kb] = *(const short8*)(WihL + off);
    }
  }

  // epilogue ownership (tid<128): sample eb (group-local), units (eu, eu+1)
  const int eb = tid >> 2;                 // 0..31 for tid<128
  const int eu = (tid & 3) * 2;
  const int gb = g * 32 + eb;              // global batch index
  float2 bg2[4];
  float hprev0 = 0.f, hprev1 = 0.f, cprev0 = 0.f, cprev1 = 0.f;
  if (tid < 128) {
    #pragma unroll
    for (int gg = 0; gg < 4; ++gg) bg2[gg] = *(const float2*)(biasg + gg * 512 + bk * 8 + eu);
    hprev0 = last[gb * 512 + bk * 8 + eu];
    hprev1 = last[gb * 512 + bk * 8 + eu + 1];
  }

  __shared__ float part[4][32][36];        // K-split partials; stride 36 -> 2-way (free)

  #pragma clang loop unroll(disable)
  for (int t = 0; t < T_; ++t) {
    const size_t ap_base = (size_t)t * 64 * KP + (size_t)g * 32 * KP;

    f32x4 acc[2][2];
    #pragma unroll
    for (int mi = 0; mi < 2; ++mi) { acc[mi][0] = (f32x4){0,0,0,0}; acc[mi][1] = (f32x4){0,0,0,0}; }

    // (A) input-side gates: xe @ W_ih^T — no dependence on other blocks
    #pragma unroll
    for (int kb = 0; kb < 3; ++kb) {
      const int k = w * 96 + kb * 32 + lq * 8;
      #pragma unroll
      for (int mi = 0; mi < 2; ++mi) {
        const size_t aoff = ap_base + (size_t)(mi * 16 + l15) * KP + k;
        short8 aH = *(const short8*)(ApH + aoff);
        short8 aL = *(const short8*)(ApL + aoff);
        #pragma unroll
        for (int n2 = 0; n2 < 2; ++n2) {
          acc[mi][n2] = __builtin_amdgcn_mfma_f32_16x16x32_bf16(aH, bihH[n2][kb], acc[mi][n2], 0, 0, 0);
          acc[mi][n2] = __builtin_amdgcn_mfma_f32_16x16x32_bf16(aH, bihL[n2][kb], acc[mi][n2], 0, 0, 0);
          acc[mi][n2] = __builtin_amdgcn_mfma_f32_16x16x32_bf16(aL, bihH[n2][kb], acc[mi][n2], 0, 0, 0);
        }
      }
    }
    const float a = (tid < 128) ? aarr[t * 64 + gb] : 0.f;

    // (B) per-wave wait: all group blocks published hx[t]  (cnt >= 64*t)
    if (t > 0) wait_cnt(cnt, (unsigned)(t * G_));

    // (C) recurrent gates: hx[t] @ W_hh^T (plain loads; per-step buffer is fresh)
    const uint16_t* hh = hxH + ((size_t)t * 2 + g) * HXG;
    const uint16_t* hl = hxL + ((size_t)t * 2 + g) * HXG;
    #pragma unroll
    for (int ks = 0; ks < 4; ++ks) {
      const int k = w * 128 + ks * 32 + lq * 8;
      #pragma unroll
      for (int mi = 0; mi < 2; ++mi) {
        const int m = mi * 16 + l15;
        short8 hH = *(const short8*)(hh + m * 512 + k);
        short8 hL = *(const short8*)(hl + m * 512 + k);
        #pragma unroll
        for (int n2 = 0; n2 < 2; ++n2) {
          acc[mi][n2] = __builtin_amdgcn_mfma_f32_16x16x32_bf16(hH, bhhH[n2][ks], acc[mi][n2], 0, 0, 0);
          acc[mi][n2] = __builtin_amdgcn_mfma_f32_16x16x32_bf16(hH, bhhL[n2][ks], acc[mi][n2], 0, 0, 0);
          acc[mi][n2] = __builtin_amdgcn_mfma_f32_16x16x32_bf16(hL, bhhH[n2][ks], acc[mi][n2], 0, 0, 0);
        }
      }
    }

    // (D) K-partials to LDS: D row=(lq*4+r)=sample, col=l15 within n-tile
    #pragma unroll
    for (int mi = 0; mi < 2; ++mi)
      #pragma unroll
      for (int n2 = 0; n2 < 2; ++n2)
        #pragma unroll
        for (int r = 0; r < 4; ++r)
          part[w][mi * 16 + lq * 4 + r][n2 * 16 + l15] = acc[mi][n2][r];

    __syncthreads();

    // (E) epilogue: gates -> gated (c,h) update; publish hx[t+1]
    if (tid < 128) {
      float gv0[4], gv1[4];
      #pragma unroll
      for (int gg = 0; gg < 4; ++gg) {
        float s0 = bg2[gg].x, s1 = bg2[gg].y;
        #pragma unroll
        for (int ww = 0; ww < 4; ++ww) {
          s0 += part[ww][eb][gg * 8 + eu];
          s1 += part[ww][eb][gg * 8 + eu + 1];
        }
        gv0[gg] = s0; gv1[gg] = s1;
      }
      float i0 = fsig(gv0[0]), f0 = fsig(gv0[1]), g0 = ftanh(gv0[2]), o0 = fsig(gv0[3]);
      float i1 = fsig(gv1[0]), f1 = fsig(gv1[1]), g1 = ftanh(gv1[2]), o1 = fsig(gv1[3]);
      float cn0 = f0 * cprev0 + i0 * g0;
      float cn1 = f1 * cprev1 + i1 * g1;
      float hn0 = o0 * ftanh(cn0);
      float hn1 = o1 * ftanh(cn1);
      float h0 = a * hn0 + (1.f - a) * hprev0;
      float h1 = a * hn1 + (1.f - a) * hprev1;
      cprev0 = a * cn0 + (1.f - a) * cprev0;
      cprev1 = a * cn1 + (1.f - a) * cprev1;
      hprev0 = h0; hprev1 = h1;

      uint16_t b0 = f2bf(h0), b1 = f2bf(h1);
      uint16_t l0 = f2bf(h0 - bf2f(b0)), l1 = f2bf(h1 - bf2f(b1));
      const size_t o = ((size_t)(t + 1) * 2 + g) * HXG + eb * 512 + bk * 8 + eu;
      st_cp((unsigned*)(hxH + o), (uint32_t)b0 | ((uint32_t)b1 << 16));
      st_cp((unsigned*)(hxL + o), (uint32_t)l0 | ((uint32_t)l1 << 16));
      if (t == T_ - 1) {
        float2 lv; lv.x = h0; lv.y = h1;
        *(float2*)(last + gb * 512 + bk * 8 + eu) = lv;
      }
    }
    if (t < T_ - 1) {
      asm volatile("s_waitcnt vmcnt(0)" ::: "memory");   // hx stores acked at MALL
      __syncthreads();                                   // whole block drained
      if (tid == 0)
        __hip_atomic_fetch_add(cnt, 1u, __ATOMIC_RELAXED, __HIP_MEMORY_SCOPE_AGENT);
    }
  }
}

// ---------------- attention between iterations (all fp32) ----------------
__global__ void att1_kernel(const float* __restrict__ last, const float* __restrict__ aW1,
                            float* __restrict__ hterm) {
  int id = blockIdx.x * 256 + threadIdx.x;           // 64*300
  if (id >= 64 * 300) return;
  int b = id / 300, e = id % 300;
  const float* lr = last + b * 512;
  const float* wr = aW1 + (size_t)e * 812 + 300;     // aW1[e, E+k]
  float s = 0.f;
  #pragma unroll 8
  for (int k = 0; k < 512; ++k) s += lr[k] * wr[k];
  hterm[b * 300 + e] = s;
}

__global__ void att2_kernel(const uint16_t* __restrict__ S1, const float* __restrict__ hterm,
                            const float* __restrict__ aW2, const float* __restrict__ ab2,
                            const float* __restrict__ amask, float* __restrict__ att) {
  int id = blockIdx.x * 128 + threadIdx.x;           // t*64+b
  if (id >= BT_) return;
  int b = id & 63;
  const uint16_t* s1 = S1 + (size_t)id * KP;         // inp@aW1[:,:E]^T + ab1 (bf16)
  const float* ht = hterm + b * 300;
  float s = ab2[0];
  for (int e = 0; e < 300; ++e) s += ftanh(bf2f(s1[e]) + ht[e]) * aW2[e];
  att[id] = amask[id] * fsig(s);
}

// ---------------- final logits (fp32 in, fp32 out) ----------------
__global__ void logits_kernel(const float* __restrict__ last, const float* __restrict__ Wout,
                              const float* __restrict__ bout, float* __restrict__ out) {
  int tid = threadIdx.x;                             // 320 = 64*5
  if (tid >= 320) return;
  int b = tid / 5, o = tid % 5;
  const float* lr = last + b * 512;
  const float* wr = Wout + o * 512;
  float s = bout[o];
  #pragma unroll 8
  for (int k = 0; k < 512; ++k) s += lr[k] * wr[k];
  out[tid] = s;
}

// ---------------- workspace layout (bytes, 256-aligned) ----------------
#define OFF_APHI  ((size_t)0)            // 16384*384*2 = 12,582,912
#define OFF_APLO  ((size_t)12582912)
#define OFF_WIHHI ((size_t)25165824)     // 2048*384*2 = 1,572,864
#define OFF_WIHLO ((size_t)26738688)
#define OFF_WHHHI ((size_t)28311552)     // 2048*512*2 = 2,097,152
#define OFF_WHHLO ((size_t)30408704)
#define OFF_AW1E  ((size_t)32505856)     // 384*384*2 = 294,912
#define OFF_S1    ((size_t)32800768)     // 16384*384*2 = 12,582,912 (bf16)
#define OFF_S1B   ((size_t)45383680)     // 1536
#define OFF_BG    ((size_t)45385216)     // 8192
#define OFF_HXH   ((size_t)45393408)     // 513*65536 = 33,619,968
#define OFF_HXL   ((size_t)79013376)     // 33,619,968
#define OFF_AMASK ((size_t)112633344)    // 65,536
#define OFF_ATT   ((size_t)112698880)    // 65,536
#define OFF_HT    ((size_t)112764416)    // 76,800
#define OFF_LAST  ((size_t)112841216)    // 131,072
#define OFF_CNT   ((size_t)112972288)    // 8,192 (2 iters x 2 groups, 256B-strided)
#define WS_NEED   ((size_t)112980480)

extern "C" void kernel_launch(void* const* d_in, const int* in_sizes, int n_in,
                              void* d_out, int out_size, void* d_ws, size_t ws_size,
                              hipStream_t stream) {
  const float* emb  = (const float*)d_in[0];
  const float* W_ih = (const float*)d_in[1];
  const float* b_ih = (const float*)d_in[2];
  const float* W_hh = (const float*)d_in[3];
  const float* b_hh = (const float*)d_in[4];
  const float* aW1  = (const float*)d_in[5];
  const float* ab1  = (const float*)d_in[6];
  const float* aW2  = (const float*)d_in[7];
  const float* ab2  = (const float*)d_in[8];
  const float* Wout = (const float*)d_in[9];
  const float* bout = (const float*)d_in[10];
  const int*   x    = (const int*)d_in[11];

  if (ws_size < WS_NEED) return;  // guarded fail: d_out stays zero (diagnostic)

  char* ws = (char*)d_ws;
  uint16_t* ApH    = (uint16_t*)(ws + OFF_APHI);
  uint16_t* ApL    = (uint16_t*)(ws + OFF_APLO);
  uint16_t* WihH   = (uint16_t*)(ws + OFF_WIHHI);
  uint16_t* WihL   = (uint16_t*)(ws + OFF_WIHLO);
  uint16_t* WhhH   = (uint16_t*)(ws + OFF_WHHHI);
  uint16_t* WhhL   = (uint16_t*)(ws + OFF_WHHLO);
  uint16_t* AW1e   = (uint16_t*)(ws + OFF_AW1E);
  uint16_t* S1     = (uint16_t*)(ws + OFF_S1);
  float*    s1bias = (float*)(ws + OFF_S1B);
  float*    biasg  = (float*)(ws + OFF_BG);
  uint16_t* HXH    = (uint16_t*)(ws + OFF_HXH);
  uint16_t* HXL    = (uint16_t*)(ws + OFF_HXL);
  float*    amask  = (float*)(ws + OFF_AMASK);
  float*    att    = (float*)(ws + OFF_ATT);
  float*    hterm  = (float*)(ws + OFF_HT);
  float*    last   = (float*)(ws + OFF_LAST);
  unsigned* cnt0   = (unsigned*)(ws + OFF_CNT);
  unsigned* cnt1   = cnt0 + 1024;

  prep_kernel<<<8226, 256, 0, stream>>>(emb, W_ih, b_ih, W_hh, b_hh, aW1, ab1, x,
                                        ApH, ApL, WihH, WihL, WhhH, WhhL, AW1e,
                                        s1bias, biasg, HXH, HXL, amask, last, cnt0);
  gemm_s1<<<dim3(3, 128), 256, 0, stream>>>(ApH, AW1e, s1bias, S1);
  // iter 0: a = pad mask; HX planes [0..256]
  rec_kernel<<<2 * G_, 256, 0, stream>>>(WhhH, WhhL, WihH, WihL, ApH, ApL,
                                         biasg, amask, HXH, HXL, last, cnt0);
  att1_kernel<<<75, 256, 0, stream>>>(last, aW1, hterm);
  att2_kernel<<<128, 128, 0, stream>>>(S1, hterm, aW2, ab2, amask, att);
  // iter 1: a = attention * mask; HX base shifted so its t=0 plane = iter0's final
  rec_kernel<<<2 * G_, 256, 0, stream>>>(WhhH, WhhL, WihH, WihL, ApH, ApL,
                                         biasg, att, HXH + (size_t)256 * HXS,
                                         HXL + (size_t)256 * HXS, last, cnt1);
  logits_kernel<<<1, 320, 0, stream>>>(last, Wout, bout, (float*)d_out);
}